// Round 13
// baseline (83.081 us; speedup 1.0000x reference)
//
#include <hip/hip_runtime.h>

#define CGN    4096
#define NBLK   256
#define NTHR   1024
#define NW     (NTHR / 64)       // 16 waves/block
#define RPB    (CGN / NBLK)      // 16 rows per block (1 per wave)
#define MAX_IT 20
#define TOLF   1e-8f

typedef float f32x4 __attribute__((ext_vector_type(4)));
typedef unsigned long long u64;

// Tagged Ap words: high 32 = epoch tag, low 32 = f32 payload, published in
// ONE 64-bit store so tag and value are never torn. Parity double-buffered.
// Overwrite-safety: block publishes epoch k+2 (parity of k) only after its
// polls of epoch k+1 passed on all its words, which requires every block to
// have published k+1, which requires every block consumed its epoch-k words.
__device__ u64      g_ap[2][CGN];
// Per-block-OWNED epoch base (the r10/r11 deadlock fix): only block blk ever
// writes g_epoch[blk], so the start-of-kernel read is race-free regardless of
// launch skew. k_done is grid-uniform (all scalars bit-identical per block),
// so all bases stay equal by induction from .bss = 0.
__device__ unsigned g_epoch[NBLK];

// Relaxed agent-scope (sc-flagged, L3 coherence point) accesses: no cache
// maintenance instructions emitted; A stays warm in L2/L3 across iterations.
#define AL32(p)   __hip_atomic_load((p), __ATOMIC_RELAXED, __HIP_MEMORY_SCOPE_AGENT)
#define AS32(p,v) __hip_atomic_store((p), (v), __ATOMIC_RELAXED, __HIP_MEMORY_SCOPE_AGENT)
#define AL64(p)   __hip_atomic_load((p), __ATOMIC_RELAXED, __HIP_MEMORY_SCOPE_AGENT)
#define AS64(p,v) __hip_atomic_store((p), (v), __ATOMIC_RELAXED, __HIP_MEMORY_SCOPE_AGENT)

__device__ __forceinline__ float wave_reduce(float v) {
    #pragma unroll
    for (int off = 32; off > 0; off >>= 1)
        v += __shfl_down(v, off, 64);
    return v;  // lane 0 holds the sum
}

// Three block-wide sums in ONE syncthreads round, broadcast to all threads.
// Fixed order => bit-identical results in every block (grid-uniform scalars).
__device__ __forceinline__ void block_sum3(float a, float b, float c,
                                           float* red, int lane, int wv,
                                           float* oa, float* ob, float* oc) {
    a = wave_reduce(a);
    b = wave_reduce(b);
    c = wave_reduce(c);
    __syncthreads();                     // protect previous use of red
    if (lane == 0) {
        red[wv]          = a;
        red[NW + wv]     = b;
        red[2 * NW + wv] = c;
    }
    __syncthreads();
    float ta = 0.f, tb = 0.f, tc = 0.f;
    #pragma unroll
    for (int i = 0; i < NW; ++i) {
        ta += red[i];
        tb += red[NW + i];
        tc += red[2 * NW + i];
    }
    *oa = ta; *ob = tb; *oc = tc;
}

__global__ __launch_bounds__(NTHR, 4) void pcg_kernel(
    const float* __restrict__ A, const float* __restrict__ b,
    float* __restrict__ x)
{
    __shared__ float p_lds[CGN];      // full p vector (mirror for matvec reads)
    __shared__ float red[3 * NW];

    const int tid  = threadIdx.x;
    const int blk  = blockIdx.x;
    const int lane = tid & 63;
    const int wv   = tid >> 6;
    const int e0   = tid * 4;                 // this thread's 4 elements
    const bool owner = (tid >> 2) == blk;     // 4 threads own the block's x-slice

    const unsigned base = AL32(&g_epoch[blk]);  // own word: race-free

    // ---- pin own A row-slice in 64 VGPRs via asm loads (not rematerializable) ----
    f32x4 arow[16];
    {
        const f32x4* bp = (const f32x4*)(A + (size_t)(blk * RPB + wv) * CGN) + lane;
        #pragma unroll
        for (int j = 0; j < 16; ++j) {
            const f32x4* addr = bp + j * 64;
            asm volatile("global_load_dwordx4 %0, %1, off"
                         : "=v"(arow[j]) : "v"(addr));
        }
    }

    // ---- init: r = b (regs), p = r (regs + LDS mirror), rs = b.b (local) ----
    f32x4 r_reg = ((const f32x4*)b)[tid];
    f32x4 p_reg = r_reg;
    f32x4 x_reg = {0.f, 0.f, 0.f, 0.f};
    *(f32x4*)&p_lds[e0] = p_reg;
    float rs, d1, d2;
    block_sum3(r_reg[0]*r_reg[0] + r_reg[1]*r_reg[1]
             + r_reg[2]*r_reg[2] + r_reg[3]*r_reg[3], 0.f, 0.f,
               red, lane, wv, &rs, &d1, &d2);
    // block_sum3's syncthreads also makes p_lds visible block-wide.

    asm volatile("s_waitcnt vmcnt(0)" ::: "memory");
    __builtin_amdgcn_sched_barrier(0);   // arow valid below this point

    unsigned kdone = 0;
    for (int k = 0; k < MAX_IT; ++k) {
        if (!(rs >= TOLF * TOLF)) break;   // uniform across grid (bit-identical rs)
        const int buf = k & 1;
        const unsigned tgt = base + (unsigned)k + 1u;

        // ---- matvec from registers: wave wv computes row blk*RPB + wv ----
        float acc = 0.f;
        #pragma unroll
        for (int j = 0; j < 16; ++j) {
            f32x4 p4 = *(const f32x4*)&p_lds[(j * 64 + lane) * 4];
            acc += arow[j][0] * p4[0] + arow[j][1] * p4[1]
                 + arow[j][2] * p4[2] + arow[j][3] * p4[3];
        }
        acc = wave_reduce(acc);
        if (lane == 0) {   // publish tagged Ap element (tag+value in one store)
            u64 w = ((u64)tgt << 32) | (u64)(unsigned)__float_as_uint(acc);
            AS64(&g_ap[buf][blk * RPB + wv], w);
        }
        // Order publish before polls: memory clobber stops compile-time
        // sinking of the store below the spin; vmcnt(0) drains it to the
        // coherence point before this wave starts consuming others' words.
        asm volatile("s_waitcnt vmcnt(0)" ::: "memory");
        __builtin_amdgcn_sched_barrier(0);

        // ---- poll own 4 tagged Ap words (dataflow sync, no barrier) ----
        f32x4 ap4;
        #pragma unroll
        for (int i = 0; i < 4; ++i) {
            u64 w = AL64(&g_ap[buf][e0 + i]);
            while ((int)((unsigned)(w >> 32) - tgt) < 0) {
                __builtin_amdgcn_s_sleep(4);
                w = AL64(&g_ap[buf][e0 + i]);
            }
            ap4[i] = __uint_as_float((unsigned)w);
        }

        // ---- fused 3-dot reduction: pAp, rAp, ApAp in one sync round ----
        float pAp, rAp, ApAp;
        block_sum3(p_reg[0]*ap4[0] + p_reg[1]*ap4[1]
                 + p_reg[2]*ap4[2] + p_reg[3]*ap4[3],
                   r_reg[0]*ap4[0] + r_reg[1]*ap4[1]
                 + r_reg[2]*ap4[2] + r_reg[3]*ap4[3],
                   ap4[0]*ap4[0] + ap4[1]*ap4[1]
                 + ap4[2]*ap4[2] + ap4[3]*ap4[3],
                   red, lane, wv, &pAp, &rAp, &ApAp);

        float ak = rs / pAp;
        // merged-dot CG identity: ||r - ak*Ap||^2 = rs - 2ak*(r.Ap) + ak^2*(Ap.Ap)
        float rs_new = rs - 2.f * ak * rAp + ak * ak * ApAp;
        float bk = rs_new / rs;
        rs = rs_new;

        // ---- local updates: x (owners), r, p; mirror p to LDS ----
        if (owner) {
            #pragma unroll
            for (int i = 0; i < 4; ++i) x_reg[i] += ak * p_reg[i];
        }
        #pragma unroll
        for (int i = 0; i < 4; ++i) {
            r_reg[i] -= ak * ap4[i];
            p_reg[i]  = r_reg[i] + bk * p_reg[i];
        }
        *(f32x4*)&p_lds[e0] = p_reg;
        __syncthreads();                  // p_lds ready for next matvec
        kdone = (unsigned)k + 1u;
    }

    // ---- advance own epoch base (only consumed by NEXT launch; stream-
    //      ordering guarantees completion before that launch begins) ----
    if (tid == 0) AS32(&g_epoch[blk], base + kdone);

    // ---- write own x slice once ----
    if (owner) *(f32x4*)&x[e0] = x_reg;
}

extern "C" void kernel_launch(void* const* d_in, const int* in_sizes, int n_in,
                              void* d_out, int out_size, void* d_ws, size_t ws_size,
                              hipStream_t stream) {
    const float* A = (const float*)d_in[0];
    const float* b = (const float*)d_in[1];
    float* x = (float*)d_out;
    pcg_kernel<<<dim3(NBLK), dim3(NTHR), 0, stream>>>(A, b, x);
}

// Round 14
// 72.100 us; speedup vs baseline: 1.1523x; 1.1523x over previous
//
#include <hip/hip_runtime.h>

#define CGN    4096
#define NBLK   256
#define NTHR   1024
#define NW     (NTHR / 64)       // 16 waves/block
#define RPB    (CGN / NBLK)      // 16 rows per block (1 per wave)
#define MAX_IT 20
#define TOLF   1e-8f

typedef float f32x4 __attribute__((ext_vector_type(4)));
typedef unsigned long long u64;

// Tagged Ap words: high 32 = epoch tag, low 32 = f32 payload, published in
// ONE 64-bit store so tag and value are never torn. Parity double-buffered.
// Overwrite-safety: block publishes epoch k+2 (parity of k) only after its
// polls of epoch k+1 passed on all its words, which requires every block to
// have published k+1, which requires every block consumed its epoch-k words.
__device__ u64      g_ap[2][CGN];
// Per-block-OWNED epoch base (r13 deadlock fix, proven): only block blk ever
// writes g_epoch[blk]; start-of-kernel read is race-free under launch skew.
// kdone is grid-uniform (bit-identical scalars) => bases stay equal.
__device__ unsigned g_epoch[NBLK];

// Relaxed agent-scope (sc-flagged, L3 coherence point) accesses: no cache
// maintenance instructions emitted; A stays warm in L2/L3 across iterations.
#define AL32(p)   __hip_atomic_load((p), __ATOMIC_RELAXED, __HIP_MEMORY_SCOPE_AGENT)
#define AS32(p,v) __hip_atomic_store((p), (v), __ATOMIC_RELAXED, __HIP_MEMORY_SCOPE_AGENT)
#define AL64(p)   __hip_atomic_load((p), __ATOMIC_RELAXED, __HIP_MEMORY_SCOPE_AGENT)
#define AS64(p,v) __hip_atomic_store((p), (v), __ATOMIC_RELAXED, __HIP_MEMORY_SCOPE_AGENT)

__device__ __forceinline__ float wave_reduce(float v) {
    #pragma unroll
    for (int off = 32; off > 0; off >>= 1)
        v += __shfl_down(v, off, 64);
    return v;  // lane 0 holds the sum
}

// Three block-wide sums in ONE syncthreads round, broadcast to all threads.
// Fixed order => bit-identical results in every block (grid-uniform scalars).
__device__ __forceinline__ void block_sum3(float a, float b, float c,
                                           float* red, int lane, int wv,
                                           float* oa, float* ob, float* oc) {
    a = wave_reduce(a);
    b = wave_reduce(b);
    c = wave_reduce(c);
    __syncthreads();                     // protect previous use of red
    if (lane == 0) {
        red[wv]          = a;
        red[NW + wv]     = b;
        red[2 * NW + wv] = c;
    }
    __syncthreads();
    float ta = 0.f, tb = 0.f, tc = 0.f;
    #pragma unroll
    for (int i = 0; i < NW; ++i) {
        ta += red[i];
        tb += red[NW + i];
        tc += red[2 * NW + i];
    }
    *oa = ta; *ob = tb; *oc = tc;
}

__global__ __launch_bounds__(NTHR, 4) void pcg_kernel(
    const float* __restrict__ A, const float* __restrict__ b,
    float* __restrict__ x)
{
    __shared__ float p_lds[CGN];      // full p vector (mirror for matvec reads)
    __shared__ float red[3 * NW];

    const int tid  = threadIdx.x;
    const int blk  = blockIdx.x;
    const int lane = tid & 63;
    const int wv   = tid >> 6;
    const int e0   = tid * 4;                 // this thread's 4 elements
    const bool owner = (tid >> 2) == blk;     // 4 threads own the block's x-slice

    const unsigned base = AL32(&g_epoch[blk]);  // own word: race-free

    // ---- pin own A row-slice in 64 VGPRs via asm loads (not rematerializable) ----
    f32x4 arow[16];
    {
        const f32x4* bp = (const f32x4*)(A + (size_t)(blk * RPB + wv) * CGN) + lane;
        #pragma unroll
        for (int j = 0; j < 16; ++j) {
            const f32x4* addr = bp + j * 64;
            asm volatile("global_load_dwordx4 %0, %1, off"
                         : "=v"(arow[j]) : "v"(addr));
        }
    }

    // ---- init: r = b (regs), p = r (regs + LDS mirror), rs = b.b (local) ----
    f32x4 r_reg = ((const f32x4*)b)[tid];
    f32x4 p_reg = r_reg;
    f32x4 x_reg = {0.f, 0.f, 0.f, 0.f};
    *(f32x4*)&p_lds[e0] = p_reg;
    float rs, d1, d2;
    block_sum3(r_reg[0]*r_reg[0] + r_reg[1]*r_reg[1]
             + r_reg[2]*r_reg[2] + r_reg[3]*r_reg[3], 0.f, 0.f,
               red, lane, wv, &rs, &d1, &d2);
    // block_sum3's syncthreads also makes p_lds visible block-wide.

    asm volatile("s_waitcnt vmcnt(0)" ::: "memory");
    __builtin_amdgcn_sched_barrier(0);   // arow valid below this point

    unsigned kdone = 0;
    for (int k = 0; k < MAX_IT; ++k) {
        if (!(rs >= TOLF * TOLF)) break;   // uniform across grid (bit-identical rs)
        const int buf = k & 1;
        const unsigned tgt = base + (unsigned)k + 1u;

        // ---- matvec from registers: wave wv computes row blk*RPB + wv ----
        float acc = 0.f;
        #pragma unroll
        for (int j = 0; j < 16; ++j) {
            f32x4 p4 = *(const f32x4*)&p_lds[(j * 64 + lane) * 4];
            acc += arow[j][0] * p4[0] + arow[j][1] * p4[1]
                 + arow[j][2] * p4[2] + arow[j][3] * p4[3];
        }
        acc = wave_reduce(acc);
        if (lane == 0) {   // publish tagged Ap element (tag+value in one store)
            u64 w = ((u64)tgt << 32) | (u64)(unsigned)__float_as_uint(acc);
            AS64(&g_ap[buf][blk * RPB + wv], w);
        }
        // Order publish before polls: memory clobber stops compile-time
        // sinking of the store below the spin; vmcnt(0) drains it to the
        // coherence point before this wave starts consuming others' words.
        asm volatile("s_waitcnt vmcnt(0)" ::: "memory");
        __builtin_amdgcn_sched_barrier(0);

        // ---- PARALLEL poll of own 4 tagged Ap words (r14 change):
        //      all 4 loads in flight per retry round -> one L3 RT, not four.
        u64 w0 = AL64(&g_ap[buf][e0 + 0]);
        u64 w1 = AL64(&g_ap[buf][e0 + 1]);
        u64 w2 = AL64(&g_ap[buf][e0 + 2]);
        u64 w3 = AL64(&g_ap[buf][e0 + 3]);
        while (((int)((unsigned)(w0 >> 32) - tgt) < 0) |
               ((int)((unsigned)(w1 >> 32) - tgt) < 0) |
               ((int)((unsigned)(w2 >> 32) - tgt) < 0) |
               ((int)((unsigned)(w3 >> 32) - tgt) < 0)) {
            __builtin_amdgcn_s_sleep(1);
            w0 = AL64(&g_ap[buf][e0 + 0]);
            w1 = AL64(&g_ap[buf][e0 + 1]);
            w2 = AL64(&g_ap[buf][e0 + 2]);
            w3 = AL64(&g_ap[buf][e0 + 3]);
        }
        f32x4 ap4;
        ap4[0] = __uint_as_float((unsigned)w0);
        ap4[1] = __uint_as_float((unsigned)w1);
        ap4[2] = __uint_as_float((unsigned)w2);
        ap4[3] = __uint_as_float((unsigned)w3);

        // ---- fused 3-dot reduction: pAp, rAp, ApAp in one sync round ----
        float pAp, rAp, ApAp;
        block_sum3(p_reg[0]*ap4[0] + p_reg[1]*ap4[1]
                 + p_reg[2]*ap4[2] + p_reg[3]*ap4[3],
                   r_reg[0]*ap4[0] + r_reg[1]*ap4[1]
                 + r_reg[2]*ap4[2] + r_reg[3]*ap4[3],
                   ap4[0]*ap4[0] + ap4[1]*ap4[1]
                 + ap4[2]*ap4[2] + ap4[3]*ap4[3],
                   red, lane, wv, &pAp, &rAp, &ApAp);

        float ak = rs / pAp;
        // merged-dot CG identity: ||r - ak*Ap||^2 = rs - 2ak*(r.Ap) + ak^2*(Ap.Ap)
        float rs_new = rs - 2.f * ak * rAp + ak * ak * ApAp;
        float bk = rs_new / rs;
        rs = rs_new;

        // ---- local updates: x (owners), r, p; mirror p to LDS ----
        if (owner) {
            #pragma unroll
            for (int i = 0; i < 4; ++i) x_reg[i] += ak * p_reg[i];
        }
        #pragma unroll
        for (int i = 0; i < 4; ++i) {
            r_reg[i] -= ak * ap4[i];
            p_reg[i]  = r_reg[i] + bk * p_reg[i];
        }
        *(f32x4*)&p_lds[e0] = p_reg;
        __syncthreads();                  // p_lds ready for next matvec
        kdone = (unsigned)k + 1u;
    }

    // ---- advance own epoch base (consumed only by the NEXT launch; stream
    //      ordering guarantees this kernel completes before that launch) ----
    if (tid == 0) AS32(&g_epoch[blk], base + kdone);

    // ---- write own x slice once ----
    if (owner) *(f32x4*)&x[e0] = x_reg;
}

extern "C" void kernel_launch(void* const* d_in, const int* in_sizes, int n_in,
                              void* d_out, int out_size, void* d_ws, size_t ws_size,
                              hipStream_t stream) {
    const float* A = (const float*)d_in[0];
    const float* b = (const float*)d_in[1];
    float* x = (float*)d_out;
    pcg_kernel<<<dim3(NBLK), dim3(NTHR), 0, stream>>>(A, b, x);
}